// Round 2
// baseline (491.186 us; speedup 1.0000x reference)
//
#include <hip/hip_runtime.h>
#include <hip/hip_bf16.h>
#include <math.h>

#define NSTREAM 4
#define DIM     1024
#define BUSW    4096
#define NTOK    8192      // B*L = 4*2048
#define NPAD    288       // 256 (res) + 4 (pre) + 4 (post) + pad
#define KSPLIT  4
#define KCH     1024      // BUSW / KSPLIT
#define BM      64
#define BK      32
#define LDA     40        // LDS leading dim (shorts): 80B rows -> conflict-free b128 reads
#define OUT0    ((size_t)16 * 2048 * 1024)   // offset of branch_input in d_out

typedef short bf16x8 __attribute__((ext_vector_type(8)));
typedef float f32x4  __attribute__((ext_vector_type(4)));

__device__ __forceinline__ unsigned short f2bf(float f) {
    union { float f; unsigned int u; } x; x.f = f;
    unsigned int r = x.u + 0x7fffu + ((x.u >> 16) & 1u);
    return (unsigned short)(r >> 16);
}
__device__ __forceinline__ unsigned int pack2(float a, float b) {
    return (unsigned int)f2bf(a) | ((unsigned int)f2bf(b) << 16);
}

// ---------------------------------------------------------------------------
// Kernel 1: pack W''[n][k] = (gamma[k]+1) * [phi_res|phi_pre|phi_post|0][k][n]
// ---------------------------------------------------------------------------
__global__ void prep_w_kernel(const float* __restrict__ gamma,
                              const float* __restrict__ phi_res,
                              const float* __restrict__ phi_pre,
                              const float* __restrict__ phi_post,
                              unsigned short* __restrict__ W) {
    int idx = blockIdx.x * 256 + threadIdx.x;    // idx = n*4096 + k
    int n = idx >> 12;
    int k = idx & 4095;
    float v = 0.0f;
    if (n < 256)      v = phi_res[k * 256 + n];
    else if (n < 260) v = phi_pre[k * 4 + (n - 256)];
    else if (n < 264) v = phi_post[k * 4 + (n - 260)];
    v *= (gamma[k] + 1.0f);
    W[idx] = f2bf(v);
}

// ---------------------------------------------------------------------------
// Kernel 2: split-K GEMM raw_part[kc][token][n], MFMA 16x16x32 bf16.
// LDS padded to LDA=40 shorts (frag reads 2-way conflict = free);
// register prefetch of next k-tile overlaps global latency with MFMA.
// ---------------------------------------------------------------------------
__launch_bounds__(256, 2)
__global__ void gemm_raw_kernel(const float* __restrict__ residuals,
                                const unsigned short* __restrict__ W,
                                float* __restrict__ raw_part) {
    __shared__ unsigned short Alds[BM * LDA];
    __shared__ unsigned short Blds[NPAD * LDA];

    const int tid = threadIdx.x;
    const int wid = tid >> 6, lane = tid & 63;
    const int tb = blockIdx.x, kc = blockIdx.y;
    const int row0 = tb * BM;

    f32x4 acc[2][9];
#pragma unroll
    for (int i = 0; i < 2; i++)
#pragma unroll
        for (int j = 0; j < 9; j++) acc[i][j] = (f32x4){0.f, 0.f, 0.f, 0.f};

    // A staging: thread -> (row = tid/4, 8 consecutive k at (tid%4)*8)
    const int arow = tid >> 2;
    const int akq  = (tid & 3) * 8;
    const int tok  = row0 + arow;
    const int bidx = tok >> 11, lidx = tok & 2047;
    const float* abase = residuals +
        (((size_t)(bidx * 4 + kc) * 2048 + lidx) * 1024 + akq);
    const unsigned short* wbase = W + (size_t)kc * KCH;

    const int fr = lane & 15, hf = lane >> 4;
    const int wr = (wid >> 1) * 32;
    const int wc = (wid & 1) * 144;

    // B staging indices (5 chunks of 256, last half-masked)
    int brn[5], bko[5];
#pragma unroll
    for (int i = 0; i < 5; i++) {
        int idx = i * 256 + tid;
        brn[i] = idx >> 2; bko[i] = (idx & 3) * 8;
    }

    float4 pf0, pf1;
    uint4 pb[5];
    // prefetch kt=0
    pf0 = *(const float4*)(abase);
    pf1 = *(const float4*)(abase + 4);
#pragma unroll
    for (int i = 0; i < 5; i++)
        if (i * 256 + tid < (NPAD * BK) / 8)
            pb[i] = *(const uint4*)(wbase + (size_t)brn[i] * BUSW + bko[i]);

    for (int kt = 0; kt < KCH / BK; kt++) {
        // commit prefetched tile to LDS
        uint4 ua;
        ua.x = pack2(pf0.x, pf0.y); ua.y = pack2(pf0.z, pf0.w);
        ua.z = pack2(pf1.x, pf1.y); ua.w = pack2(pf1.z, pf1.w);
        *(uint4*)&Alds[arow * LDA + akq] = ua;
#pragma unroll
        for (int i = 0; i < 5; i++)
            if (i * 256 + tid < (NPAD * BK) / 8)
                *(uint4*)&Blds[brn[i] * LDA + bko[i]] = pb[i];
        __syncthreads();

        // issue next tile's global loads (overlap with ds_read+MFMA)
        if (kt + 1 < KCH / BK) {
            const float* ap = abase + (kt + 1) * BK;
            pf0 = *(const float4*)(ap);
            pf1 = *(const float4*)(ap + 4);
#pragma unroll
            for (int i = 0; i < 5; i++)
                if (i * 256 + tid < (NPAD * BK) / 8)
                    pb[i] = *(const uint4*)(wbase + (size_t)brn[i] * BUSW +
                                            (kt + 1) * BK + bko[i]);
        }

        bf16x8 afrag[2], bfrag[9];
#pragma unroll
        for (int mt = 0; mt < 2; mt++)
            afrag[mt] = *(const bf16x8*)&Alds[(wr + mt * 16 + fr) * LDA + hf * 8];
#pragma unroll
        for (int nt = 0; nt < 9; nt++)
            bfrag[nt] = *(const bf16x8*)&Blds[(wc + nt * 16 + fr) * LDA + hf * 8];
#pragma unroll
        for (int mt = 0; mt < 2; mt++)
#pragma unroll
            for (int nt = 0; nt < 9; nt++)
                acc[mt][nt] = __builtin_amdgcn_mfma_f32_16x16x32_bf16(
                    afrag[mt], bfrag[nt], acc[mt][nt], 0, 0, 0);
        __syncthreads();
    }

    // epilogue: C/D mapping col=lane&15, row=(lane>>4)*4+reg
#pragma unroll
    for (int mt = 0; mt < 2; mt++)
#pragma unroll
        for (int nt = 0; nt < 9; nt++)
#pragma unroll
            for (int r = 0; r < 4; r++) {
                int token = row0 + wr + mt * 16 + hf * 4 + r;
                int col   = wc + nt * 16 + fr;
                raw_part[((size_t)kc * NTOK + token) * NPAD + col] = acc[mt][nt][r];
            }
}

// ---------------------------------------------------------------------------
// Kernel 3: wave-per-token fused tail. 2048 blocks x 256 thr (4 waves = 4 tokens).
// Barrier-free, no LDS: bus in registers, Sinkhorn via shuffle butterflies.
// Lane l owns raw cols n = l*4..l*4+3  -> Z row r=l>>2, cols tc=(l&3)*4+j,
// and bus positions c = l*4..l*4+3 of every 256-wide chunk.
// ---------------------------------------------------------------------------
__launch_bounds__(256, 4)
__global__ void fused_tail_kernel(const float* __restrict__ residuals,
                                  const float* __restrict__ branch_output,
                                  const float* __restrict__ H_res_logits,
                                  const float* __restrict__ alpha_res_p,
                                  const float* __restrict__ H_pre_logits,
                                  const float* __restrict__ alpha_pre_p,
                                  const float* __restrict__ H_post_logits,
                                  const float* __restrict__ alpha_post_p,
                                  const float* __restrict__ raw_part,
                                  float* __restrict__ out) {
    const int wid = threadIdx.x >> 6, lane = threadIdx.x & 63;
    const int t = blockIdx.x * 4 + wid;
    const int b = t >> 11, lt = t & 2047;

    // ---- load bus into registers (16 chunk-float4s) + sumsq
    const float* rbase = residuals + ((size_t)b * 4 * 2048 + lt) * 1024;
    float4 busr[16];
    float sumsq = 0.f;
#pragma unroll
    for (int s = 0; s < 4; s++)
#pragma unroll
        for (int q = 0; q < 4; q++) {
            float4 v = *(const float4*)(rbase + (size_t)s * 2048 * 1024 + q * 256 + lane * 4);
            busr[s * 4 + q] = v;
            sumsq += v.x * v.x + v.y * v.y + v.z * v.z + v.w * v.w;
        }
#pragma unroll
    for (int m = 1; m < 64; m <<= 1) sumsq += __shfl_xor(sumsq, m, 64);
    const float scale = 64.0f / fmaxf(sqrtf(sumsq), 1e-12f);

    // ---- raw row (sum split-K partials) + extras
    float4 zr = {0.f, 0.f, 0.f, 0.f}, ep = {0.f, 0.f, 0.f, 0.f}, eq = {0.f, 0.f, 0.f, 0.f};
#pragma unroll
    for (int kc = 0; kc < 4; kc++) {
        const float* p = raw_part + ((size_t)kc * NTOK + t) * NPAD;
        float4 a = *(const float4*)(p + lane * 4);
        zr.x += a.x; zr.y += a.y; zr.z += a.z; zr.w += a.w;
        float4 e0 = *(const float4*)(p + 256);
        float4 e1 = *(const float4*)(p + 260);
        ep.x += e0.x; ep.y += e0.y; ep.z += e0.z; ep.w += e0.w;
        eq.x += e1.x; eq.y += e1.y; eq.z += e1.z; eq.w += e1.w;
    }

    const float a_res = alpha_res_p[0];
    float4 hres = *(const float4*)(H_res_logits + lane * 4);
    float Z[4];
    Z[0] = (a_res * scale * zr.x + hres.x) * 20.0f;
    Z[1] = (a_res * scale * zr.y + hres.y) * 20.0f;
    Z[2] = (a_res * scale * zr.z + hres.z) * 20.0f;
    Z[3] = (a_res * scale * zr.w + hres.w) * 20.0f;

    // ---- H_pre / H_post softmax (redundant per lane, trivial)
    float hpre[4], hpost[4];
    {
        const float apre = alpha_pre_p[0], apost = alpha_post_p[0];
        float4 hpl = *(const float4*)(H_pre_logits);
        float4 hql = *(const float4*)(H_post_logits);
        float pv[4] = { apre * scale * ep.x + hpl.x, apre * scale * ep.y + hpl.y,
                        apre * scale * ep.z + hpl.z, apre * scale * ep.w + hpl.w };
        float qv[4] = { apost * scale * eq.x + hql.x, apost * scale * eq.y + hql.y,
                        apost * scale * eq.z + hql.z, apost * scale * eq.w + hql.w };
        float pm = fmaxf(fmaxf(pv[0], pv[1]), fmaxf(pv[2], pv[3]));
        float qm = fmaxf(fmaxf(qv[0], qv[1]), fmaxf(qv[2], qv[3]));
        float ps = 0.f, qs = 0.f;
#pragma unroll
        for (int s = 0; s < 4; s++) {
            pv[s] = __expf(pv[s] - pm); qv[s] = __expf(qv[s] - qm);
            ps += pv[s]; qs += qv[s];
        }
#pragma unroll
        for (int s = 0; s < 4; s++) { hpre[s] = pv[s] / ps; hpost[s] = qv[s] / qs; }
    }

    // ---- Sinkhorn (10 iters) fully in-wave.
    const float lm = -2.772588722239781f;  // -log(16)
    float vv[4] = {0.f, 0.f, 0.f, 0.f};
    float u = 0.f;
#pragma unroll
    for (int it = 0; it < 10; it++) {
        // u-phase: LSE over the 16 cols of row r (this lane + xor1/xor2 partners)
        float m0 = fmaxf(fmaxf(Z[0] + vv[0], Z[1] + vv[1]),
                         fmaxf(Z[2] + vv[2], Z[3] + vv[3]));
        m0 = fmaxf(m0, __shfl_xor(m0, 1, 64));
        m0 = fmaxf(m0, __shfl_xor(m0, 2, 64));
        float s0 = __expf(Z[0] + vv[0] - m0) + __expf(Z[1] + vv[1] - m0) +
                   __expf(Z[2] + vv[2] - m0) + __expf(Z[3] + vv[3] - m0);
        s0 += __shfl_xor(s0, 1, 64);
        s0 += __shfl_xor(s0, 2, 64);
        u = lm - (m0 + __logf(s0));
        // v-phase: LSE over 16 rows for each of this lane's 4 cols (xor 4..32)
        float cm[4], cs[4];
#pragma unroll
        for (int j = 0; j < 4; j++) cm[j] = Z[j] + u;
#pragma unroll
        for (int msk = 4; msk < 64; msk <<= 1)
#pragma unroll
            for (int j = 0; j < 4; j++) cm[j] = fmaxf(cm[j], __shfl_xor(cm[j], msk, 64));
#pragma unroll
        for (int j = 0; j < 4; j++) cs[j] = __expf(Z[j] + u - cm[j]);
#pragma unroll
        for (int msk = 4; msk < 64; msk <<= 1)
#pragma unroll
            for (int j = 0; j < 4; j++) cs[j] += __shfl_xor(cs[j], msk, 64);
#pragma unroll
        for (int j = 0; j < 4; j++) vv[j] = lm - (cm[j] + __logf(cs[j]));
    }
    float S[4];
#pragma unroll
    for (int j = 0; j < 4; j++) S[j] = __expf(Z[j] + u + vv[j]) * 16.0f;

    // ---- mixing + branch add + stores (all dwordx4)
    const float* bob = branch_output + ((size_t)b * 2048 + lt) * 1024;
    float* outb = out; // full out
#pragma unroll
    for (int q = 0; q < 4; q++) {
        float4 bv = *(const float4*)(bob + q * 256 + lane * 4);
#pragma unroll
        for (int so = 0; so < 4; so++) {
            // chunk m = so*4+q ; S[s_in][m] lives in lane s_in*4+so, component q
            float4 acc;
            float hp = hpost[so];
            acc.x = hp * bv.x; acc.y = hp * bv.y; acc.z = hp * bv.z; acc.w = hp * bv.w;
#pragma unroll
            for (int n = 0; n < 16; n++) {
                float sv = __shfl(S[q], n * 4 + so, 64);
                float4 bu = busr[n];
                acc.x += sv * bu.x; acc.y += sv * bu.y;
                acc.z += sv * bu.z; acc.w += sv * bu.w;
            }
            *(float4*)(outb + ((size_t)(b * 4 + so) * 2048 + lt) * 1024 +
                       q * 256 + lane * 4) = acc;
        }
    }

    // ---- branch_input
#pragma unroll
    for (int q = 0; q < 4; q++) {
        float4 bi = {0.f, 0.f, 0.f, 0.f};
#pragma unroll
        for (int s = 0; s < 4; s++) {
            float4 v = busr[s * 4 + q];
            float h = hpre[s];
            bi.x += h * v.x; bi.y += h * v.y; bi.z += h * v.z; bi.w += h * v.w;
        }
        *(float4*)(outb + OUT0 + ((size_t)b * 2048 + lt) * 1024 + q * 256 + lane * 4) = bi;
    }
}

// ---------------------------------------------------------------------------
extern "C" void kernel_launch(void* const* d_in, const int* in_sizes, int n_in,
                              void* d_out, int out_size, void* d_ws, size_t ws_size,
                              hipStream_t stream) {
    const float* residuals  = (const float*)d_in[0];
    const float* branch_out = (const float*)d_in[1];
    const float* gamma      = (const float*)d_in[2];
    const float* H_res_log  = (const float*)d_in[3];
    const float* phi_res    = (const float*)d_in[4];
    const float* alpha_res  = (const float*)d_in[5];
    const float* H_pre_log  = (const float*)d_in[6];
    const float* phi_pre    = (const float*)d_in[7];
    const float* alpha_pre  = (const float*)d_in[8];
    const float* H_post_log = (const float*)d_in[9];
    const float* phi_post   = (const float*)d_in[10];
    const float* alpha_post = (const float*)d_in[11];

    unsigned short* W = (unsigned short*)d_ws;                         // 288*4096 bf16
    float* raw_part = (float*)((char*)d_ws + (size_t)NPAD * BUSW * 2); // 4*8192*288 f32
    float* out = (float*)d_out;

    hipLaunchKernelGGL(prep_w_kernel, dim3(NPAD * BUSW / 256), dim3(256), 0, stream,
                       gamma, phi_res, phi_pre, phi_post, W);
    hipLaunchKernelGGL(gemm_raw_kernel, dim3(NTOK / BM, KSPLIT), dim3(256), 0, stream,
                       residuals, W, raw_part);
    hipLaunchKernelGGL(fused_tail_kernel, dim3(NTOK / 4), dim3(256), 0, stream,
                       residuals, branch_out, H_res_log, alpha_res,
                       H_pre_log, alpha_pre, H_post_log, alpha_post, raw_part, out);
}